// Round 1
// baseline (682.950 us; speedup 1.0000x reference)
//
#include <hip/hip_runtime.h>
#include <hip/hip_bf16.h>
#include <stdint.h>

// Problem constants (match reference)
#define BN   4096
#define SN   200
#define SPAD 224      // 7 s-tiles of 32
#define EN   128
#define HN   128      // ATT_H

typedef __attribute__((ext_vector_type(8)))  short  short8;
typedef __attribute__((ext_vector_type(16))) float  floatx16;

__device__ __forceinline__ unsigned short f2bf(float f) {
  union { float f; uint32_t u; } c; c.f = f;
  uint32_t r = c.u + 0x7fffu + ((c.u >> 16) & 1u);   // RNE
  return (unsigned short)(r >> 16);
}
__device__ __forceinline__ float bf2f(unsigned short h) {
  union { uint32_t u; float f; } c; c.u = ((uint32_t)h) << 16;
  return c.f;
}
__device__ __forceinline__ float bcast_lane(float v, int l) {
  return __builtin_bit_cast(float, __builtin_amdgcn_readlane(__builtin_bit_cast(int, v), l));
}

// LDS byte offset of 16B chunk g (g = e>>3) of row s, XOR-16 swizzled.
// Row stride 256B; swizzle keeps b128 reads at <=2..4-way bank aliasing.
__device__ __forceinline__ int aoff(int s, int g) {
  return s * 256 + (((g ^ (s & 15)) << 4));
}

// ---------------------------------------------------------------------------
// Kernel 1: per-batch-row attention. One block = one b.
//   scores via bf16 MFMA (C cols = s so h-reduction is in-lane),
//   softmax, user_interest (fp32 accum over bf16 LDS), ui -> workspace.
// ---------------------------------------------------------------------------
__global__ __launch_bounds__(256, 2)
void din_main(const float* __restrict__ behavior, const float* __restrict__ cand,
              const float* __restrict__ fc1w, const float* __restrict__ fc1b,
              const float* __restrict__ fc2w, float* __restrict__ ws_ui) {
  __shared__ unsigned short Abuf[SPAD * EN];   // 57344 B, bf16 behavior (swizzled)
  __shared__ float scores_s[SPAD];
  __shared__ float cvec[HN];                   // cand @ W_c + fc1_b
  __shared__ float w2s[HN];
  __shared__ float cand_s[EN];
  __shared__ float ui_s[EN];

  const int tid = threadIdx.x;
  const int b   = blockIdx.x;

  if (tid < SPAD) scores_s[tid] = 0.f;
  if (tid < EN) {
    cand_s[tid] = cand[(size_t)b * EN + tid];
    w2s[tid]    = fc2w[tid];
    ui_s[tid]   = 0.f;
  }
  __syncthreads();

  // ---- stage behavior[b] -> bf16 LDS (zeros for padded rows 200..223) ----
  {
    const float* src = behavior + (size_t)b * SN * EN;
    #pragma unroll
    for (int it = 0; it < 28; ++it) {          // 224*128/4 = 7168 float4 slots
      int q  = it * 256 + tid;
      int s  = q >> 5;
      int e4 = (q & 31) << 2;
      float4 v = make_float4(0.f, 0.f, 0.f, 0.f);
      if (s < SN) v = *(const float4*)(src + s * EN + e4);
      uint32_t p0 = (uint32_t)f2bf(v.x) | ((uint32_t)f2bf(v.y) << 16);
      uint32_t p1 = (uint32_t)f2bf(v.z) | ((uint32_t)f2bf(v.w) << 16);
      char* dst = (char*)Abuf + s * 256 + ((((e4 >> 3) ^ (s & 15))) << 4) + ((e4 & 7) << 1);
      *(uint2*)dst = make_uint2(p0, p1);
    }
  }

  // ---- cvec[h] = cand . W_c[:,h] + fc1_b[h]  (threads 0..127, fp32) ----
  if (tid < HN) {
    float a = fc1b[tid];
    for (int e = 0; e < EN; ++e)
      a = fmaf(cand_s[e], fc1w[(EN + e) * HN + tid], a);
    cvec[tid] = a;
  }
  __syncthreads();

  // ---- phase 1: scores = relu(beh@Wb + cvec) . fc2w via MFMA ----
  const int wv   = tid >> 6;         // wave 0..3 = h-tile
  const int lane = tid & 63;
  const int half = lane >> 5;        // 0/1
  const int l31  = lane & 31;

  // A = W_b^T m-tile (32 h x 128 e) in registers: A[m=lane&31][k=8*half+j], k-step t
  const int hcol = wv * 32 + l31;
  short8 afr[8];
  #pragma unroll
  for (int t = 0; t < 8; ++t) {
    #pragma unroll
    for (int j = 0; j < 8; ++j) {
      int e = t * 16 + half * 8 + j;
      afr[t][j] = (short)f2bf(fc1w[e * HN + hcol]);
    }
  }
  // epilogue constants: lane's 16 h rows (C/D: row=(r&3)+8*(r>>2)+4*half)
  float cadd[16], wmul[16];
  #pragma unroll
  for (int r = 0; r < 16; ++r) {
    int hr = wv * 32 + (r & 3) + ((r >> 2) << 3) + (half << 2);
    cadd[r] = cvec[hr];
    wmul[r] = w2s[hr];
  }

  for (int st = 0; st < 7; ++st) {
    floatx16 acc = {0.f,0.f,0.f,0.f,0.f,0.f,0.f,0.f,0.f,0.f,0.f,0.f,0.f,0.f,0.f,0.f};
    const int srow = st * 32 + l31;  // B fragment: n = lane&31 = s
    #pragma unroll
    for (int t = 0; t < 8; ++t) {
      int g = 2 * t + half;          // e chunk: e = 16t + 8*half + j
      const short8 bfr = *(const short8*)((const char*)Abuf + aoff(srow, g));
      acc = __builtin_amdgcn_mfma_f32_32x32x16_bf16(afr[t], bfr, acc, 0, 0, 0);
    }
    float part = 0.f;
    #pragma unroll
    for (int r = 0; r < 16; ++r) {
      float h = fmaxf(acc[r] + cadd[r], 0.f);
      part = fmaf(h, wmul[r], part);
    }
    part += __shfl_xor(part, 32, 64);          // combine the two half-wave h-sets
    if (lane < 32) atomicAdd(&scores_s[st * 32 + l31], part);
  }
  __syncthreads();

  // ---- phase 2: softmax over s<200 (wave 0) ----
  if (wv == 0) {
    float v0[4];
    #pragma unroll
    for (int k = 0; k < 4; ++k) {
      int s = k * 64 + lane;
      v0[k] = (s < SN) ? scores_s[s] : -3.0e38f;
    }
    float m = fmaxf(fmaxf(v0[0], v0[1]), fmaxf(v0[2], v0[3]));
    #pragma unroll
    for (int off = 32; off >= 1; off >>= 1) m = fmaxf(m, __shfl_xor(m, off, 64));
    float e0[4], sum = 0.f;
    #pragma unroll
    for (int k = 0; k < 4; ++k) { e0[k] = __expf(v0[k] - m); sum += e0[k]; }
    #pragma unroll
    for (int off = 32; off >= 1; off >>= 1) sum += __shfl_xor(sum, off, 64);
    float inv = 1.0f / sum;
    #pragma unroll
    for (int k = 0; k < 4; ++k) {
      int s = k * 64 + lane;
      if (s < SN) scores_s[s] = e0[k] * inv;   // overwrite with attn
    }
  }
  __syncthreads();

  // ---- phase 3: user_interest[e] = sum_s attn[s]*behavior[s][e] ----
  {
    const int ec = (tid & 15) << 3;            // 8-wide e chunk
    const int sg = tid >> 4;                   // s stride group 0..15
    float ua[8] = {0.f,0.f,0.f,0.f,0.f,0.f,0.f,0.f};
    for (int s = sg; s < SN; s += 16) {
      float a = scores_s[s];
      const short8 bv = *(const short8*)((const char*)Abuf + aoff(s, ec >> 3));
      #pragma unroll
      for (int j = 0; j < 8; ++j) ua[j] = fmaf(a, bf2f((unsigned short)bv[j]), ua[j]);
    }
    #pragma unroll
    for (int j = 0; j < 8; ++j) atomicAdd(&ui_s[ec + j], ua[j]);
  }
  __syncthreads();
  if (tid < EN) ws_ui[(size_t)b * EN + tid] = ui_s[tid];
}

// ---------------------------------------------------------------------------
// Kernel 2: MLP head. Block = 8 batch rows; thread j owns output column j.
// x broadcast via v_readlane (VALU pipe), mlp1_w loads coalesced across j.
// ---------------------------------------------------------------------------
__global__ __launch_bounds__(256, 2)
void din_mlp(const float* __restrict__ ws_ui, const float* __restrict__ cand,
             const float* __restrict__ w1, const float* __restrict__ b1,
             const float* __restrict__ w2, const float* __restrict__ b2,
             float* __restrict__ out) {
  const int tid  = threadIdx.x;
  const int lane = tid & 63;
  const int wv   = tid >> 6;
  const int r0   = blockIdx.x * 8;

  // x[r][i], i = c*64+lane ; x = [ui(128) | cand(128)]
  float xr[8][4];
  #pragma unroll
  for (int r = 0; r < 8; ++r) {
    #pragma unroll
    for (int c = 0; c < 4; ++c) {
      int i = c * 64 + lane;
      int row = r0 + r;
      xr[r][c] = (i < 128) ? ws_ui[row * 128 + i] : cand[row * 128 + (i - 128)];
    }
  }

  const int j = tid;
  float acc[8];
  const float bj = b1[j];
  #pragma unroll
  for (int r = 0; r < 8; ++r) acc[r] = bj;

  #pragma unroll
  for (int c = 0; c < 4; ++c) {
    #pragma unroll 8
    for (int il = 0; il < 64; ++il) {
      float w = w1[(c * 64 + il) * 256 + j];
      #pragma unroll
      for (int r = 0; r < 8; ++r)
        acc[r] = fmaf(bcast_lane(xr[r][c], il), w, acc[r]);
    }
  }

  const float w2j = w2[j];
  float part[8];
  #pragma unroll
  for (int r = 0; r < 8; ++r) part[r] = fmaxf(acc[r], 0.f) * w2j;
  #pragma unroll
  for (int off = 32; off >= 1; off >>= 1) {
    #pragma unroll
    for (int r = 0; r < 8; ++r) part[r] += __shfl_xor(part[r], off, 64);
  }

  __shared__ float red[4][8];
  if (lane == 0) {
    #pragma unroll
    for (int r = 0; r < 8; ++r) red[wv][r] = part[r];
  }
  __syncthreads();
  if (tid < 8)
    out[r0 + tid] = red[0][tid] + red[1][tid] + red[2][tid] + red[3][tid] + b2[0];
}

extern "C" void kernel_launch(void* const* d_in, const int* in_sizes, int n_in,
                              void* d_out, int out_size, void* d_ws, size_t ws_size,
                              hipStream_t stream) {
  const float* behavior = (const float*)d_in[0];
  const float* cand     = (const float*)d_in[1];
  const float* fc1w     = (const float*)d_in[2];
  const float* fc1b     = (const float*)d_in[3];
  const float* fc2w     = (const float*)d_in[4];
  // d_in[5] = fc2_b: constant shift before softmax -> no-op, skipped
  const float* m1w      = (const float*)d_in[6];
  const float* m1b      = (const float*)d_in[7];
  const float* m2w      = (const float*)d_in[8];
  const float* m2b      = (const float*)d_in[9];
  float* outp  = (float*)d_out;
  float* ws_ui = (float*)d_ws;              // 4096*128 fp32 = 2 MB

  din_main<<<BN, 256, 0, stream>>>(behavior, cand, fc1w, fc1b, fc2w, ws_ui);
  din_mlp<<<BN / 8, 256, 0, stream>>>(ws_ui, cand, m1w, m1b, m2w, m2b, outp);
}

// Round 2
// 620.523 us; speedup vs baseline: 1.1006x; 1.1006x over previous
//
#include <hip/hip_runtime.h>
#include <hip/hip_bf16.h>
#include <stdint.h>

// Problem constants (match reference)
#define BN   4096
#define SN   200
#define EN   128
#define HN   128      // ATT_H

typedef __attribute__((ext_vector_type(8)))  short  short8;
typedef __attribute__((ext_vector_type(16))) float  floatx16;

__device__ __forceinline__ unsigned short f2bf(float f) {
  union { float f; uint32_t u; } c; c.f = f;
  uint32_t r = c.u + 0x7fffu + ((c.u >> 16) & 1u);   // RNE
  return (unsigned short)(r >> 16);
}
__device__ __forceinline__ float bf2f(unsigned short h) {
  union { uint32_t u; float f; } c; c.u = ((uint32_t)h) << 16;
  return c.f;
}
__device__ __forceinline__ float bcast_lane(float v, int l) {
  return __builtin_bit_cast(float, __builtin_amdgcn_readlane(__builtin_bit_cast(int, v), l));
}

// LDS byte offset of 16B chunk g (g = e>>3) of row s, XOR-16 swizzled.
__device__ __forceinline__ int aoff(int s, int g) {
  return s * 256 + (((g ^ (s & 15)) << 4));
}

// ---------------------------------------------------------------------------
// Prep: repack W_b^T into bf16 MFMA A-fragment layout, once for all blocks.
// ws_afr[(wv*8+t)*64 + lane] = short8 {A[m=wv*32+(lane&31)][k=t*16+(lane>>5)*8+j]}
// grid 32 blocks x 64 threads: bid -> (t = bid&7, wv = bid>>3)
// ---------------------------------------------------------------------------
__global__ void din_prep(const float* __restrict__ fc1w, short8* __restrict__ ws_afr) {
  const int t    = blockIdx.x & 7;
  const int wv   = blockIdx.x >> 3;
  const int lane = threadIdx.x;      // 0..63
  const int half = lane >> 5;
  const int hcol = wv * 32 + (lane & 31);
  short8 fr;
  #pragma unroll
  for (int j = 0; j < 8; ++j) {
    int e = t * 16 + half * 8 + j;
    fr[j] = (short)f2bf(fc1w[e * HN + hcol]);
  }
  ws_afr[((wv * 8 + t) << 6) + lane] = fr;
}

// ---------------------------------------------------------------------------
// Kernel 1: per-batch-row attention. One block = one b. 3 blocks/CU.
// ---------------------------------------------------------------------------
__global__ __launch_bounds__(256, 3)
void din_main(const float* __restrict__ behavior, const float* __restrict__ cand,
              const float* __restrict__ fc1w, const float* __restrict__ fc1b,
              const float* __restrict__ fc2w, const short8* __restrict__ ws_afr,
              float* __restrict__ ws_ui) {
  __shared__ unsigned short Abuf[SN * EN];     // 51200 B bf16 behavior (swizzled)
  __shared__ float scores_s[SN];               // 800 B
  __shared__ float cvec2[2][HN];               // 1024 B: cand@W_c+fc1_b, 2 e-halves
  __shared__ float cand_s[EN];                 // 512 B
  __shared__ float ui_s[EN];                   // 512 B   -> total 54048 B

  const int tid = threadIdx.x;
  const int b   = blockIdx.x;

  if (tid < SN) scores_s[tid] = 0.f;
  if (tid < EN) {
    cand_s[tid] = cand[(size_t)b * EN + tid];
    ui_s[tid]   = 0.f;
  }
  __syncthreads();

  const int wv   = tid >> 6;
  const int lane = tid & 63;
  const int half = lane >> 5;
  const int l31  = lane & 31;

  // ---- stage behavior[b]: batch A loads (13 float4) issued first ----
  const float* src = behavior + (size_t)b * SN * EN;
  float4 va[13];
  #pragma unroll
  for (int u = 0; u < 13; ++u) {
    int q = u * 256 + tid;
    va[u] = *(const float4*)(src + (q >> 5) * EN + ((q & 31) << 2));
  }
  // A-fragments from ws (coalesced b128, completes under HBM latency)
  short8 afr[8];
  #pragma unroll
  for (int t = 0; t < 8; ++t) afr[t] = ws_afr[((wv * 8 + t) << 6) + lane];

  // ---- cvec: h = tid&127, e-half = tid>>7; 64 fma, coalesced fc1w loads ----
  {
    const int h  = tid & 127;
    const int eh = tid >> 7;
    float p0 = (eh == 0) ? fc1b[h] : 0.f, p1 = 0.f;
    const float* wc = fc1w + (size_t)(EN + eh * 64) * HN + h;
    #pragma unroll 8
    for (int e = 0; e < 64; e += 2) {
      p0 = fmaf(cand_s[eh * 64 + e],     wc[(size_t)e * HN],       p0);
      p1 = fmaf(cand_s[eh * 64 + e + 1], wc[(size_t)(e + 1) * HN], p1);
    }
    cvec2[eh][h] = p0 + p1;
  }

  // ---- convert+store batch A, then batch B ----
  #pragma unroll
  for (int u = 0; u < 13; ++u) {
    int q = u * 256 + tid, s = q >> 5, e4 = (q & 31) << 2;
    uint32_t p0 = (uint32_t)f2bf(va[u].x) | ((uint32_t)f2bf(va[u].y) << 16);
    uint32_t p1 = (uint32_t)f2bf(va[u].z) | ((uint32_t)f2bf(va[u].w) << 16);
    char* dst = (char*)Abuf + s * 256 + ((((e4 >> 3) ^ (s & 15))) << 4) + ((e4 & 7) << 1);
    *(uint2*)dst = make_uint2(p0, p1);
  }
  float4 vb[12];
  #pragma unroll
  for (int u = 0; u < 12; ++u) {
    int q = (u + 13) * 256 + tid;
    vb[u] = *(const float4*)(src + (q >> 5) * EN + ((q & 31) << 2));
  }
  #pragma unroll
  for (int u = 0; u < 12; ++u) {
    int q = (u + 13) * 256 + tid, s = q >> 5, e4 = (q & 31) << 2;
    uint32_t p0 = (uint32_t)f2bf(vb[u].x) | ((uint32_t)f2bf(vb[u].y) << 16);
    uint32_t p1 = (uint32_t)f2bf(vb[u].z) | ((uint32_t)f2bf(vb[u].w) << 16);
    char* dst = (char*)Abuf + s * 256 + ((((e4 >> 3) ^ (s & 15))) << 4) + ((e4 & 7) << 1);
    *(uint2*)dst = make_uint2(p0, p1);
  }
  __syncthreads();

  // ---- phase 1: scores via MFMA (C cols = s, h-reduction in-lane) ----
  float cadd[16], wmul[16];
  #pragma unroll
  for (int r = 0; r < 16; ++r) {
    int hr = wv * 32 + (r & 3) + ((r >> 2) << 3) + (half << 2);
    cadd[r] = cvec2[0][hr] + cvec2[1][hr];
    wmul[r] = fc2w[hr];
  }

  for (int st = 0; st < 7; ++st) {
    floatx16 acc = {0.f,0.f,0.f,0.f,0.f,0.f,0.f,0.f,0.f,0.f,0.f,0.f,0.f,0.f,0.f,0.f};
    const int srow = st * 32 + l31;
    const int sr   = (srow < SN) ? srow : (SN - 1);   // clamp; garbage scores masked
    #pragma unroll
    for (int t = 0; t < 8; ++t) {
      int g = 2 * t + half;
      const short8 bfr = *(const short8*)((const char*)Abuf + aoff(sr, g));
      acc = __builtin_amdgcn_mfma_f32_32x32x16_bf16(afr[t], bfr, acc, 0, 0, 0);
    }
    float part = 0.f;
    #pragma unroll
    for (int r = 0; r < 16; ++r) {
      float h = fmaxf(acc[r] + cadd[r], 0.f);
      part = fmaf(h, wmul[r], part);
    }
    part += __shfl_xor(part, 32, 64);
    if (lane < 32 && srow < SN) atomicAdd(&scores_s[srow], part);
  }
  __syncthreads();

  // ---- phase 2: softmax over s<200 (wave 0) ----
  if (wv == 0) {
    float v0[4];
    #pragma unroll
    for (int k = 0; k < 4; ++k) {
      int s = k * 64 + lane;
      v0[k] = (s < SN) ? scores_s[s] : -3.0e38f;
    }
    float m = fmaxf(fmaxf(v0[0], v0[1]), fmaxf(v0[2], v0[3]));
    #pragma unroll
    for (int off = 32; off >= 1; off >>= 1) m = fmaxf(m, __shfl_xor(m, off, 64));
    float e0[4], sum = 0.f;
    #pragma unroll
    for (int k = 0; k < 4; ++k) { e0[k] = __expf(v0[k] - m); sum += e0[k]; }
    #pragma unroll
    for (int off = 32; off >= 1; off >>= 1) sum += __shfl_xor(sum, off, 64);
    float inv = 1.0f / sum;
    #pragma unroll
    for (int k = 0; k < 4; ++k) {
      int s = k * 64 + lane;
      if (s < SN) scores_s[s] = e0[k] * inv;   // attn
    }
  }
  __syncthreads();

  // ---- phase 3: ui[e] = sum_s attn[s]*beh[s][e]; shuffle pre-reduce ----
  {
    const int g  = tid & 15;                   // e-chunk (8 wide)
    const int sg = tid >> 4;                   // s stride group 0..15
    float ua[8] = {0.f,0.f,0.f,0.f,0.f,0.f,0.f,0.f};
    for (int s = sg; s < SN; s += 16) {
      float a = scores_s[s];
      const short8 bv = *(const short8*)((const char*)Abuf + aoff(s, g));
      #pragma unroll
      for (int j = 0; j < 8; ++j) ua[j] = fmaf(a, bf2f((unsigned short)bv[j]), ua[j]);
    }
    #pragma unroll
    for (int j = 0; j < 8; ++j) {
      ua[j] += __shfl_xor(ua[j], 16, 64);
      ua[j] += __shfl_xor(ua[j], 32, 64);
    }
    if (lane < 16) {
      #pragma unroll
      for (int j = 0; j < 8; ++j) atomicAdd(&ui_s[(g << 3) + j], ua[j]);
    }
  }
  __syncthreads();
  if (tid < EN) ws_ui[(size_t)b * EN + tid] = ui_s[tid];
}

// ---------------------------------------------------------------------------
// Kernel 2: MLP head. Block = 4 batch rows (1024 blocks, 4/CU).
// ---------------------------------------------------------------------------
__global__ __launch_bounds__(256, 4)
void din_mlp(const float* __restrict__ ws_ui, const float* __restrict__ cand,
             const float* __restrict__ w1, const float* __restrict__ b1,
             const float* __restrict__ w2, const float* __restrict__ b2,
             float* __restrict__ out) {
  const int tid  = threadIdx.x;
  const int lane = tid & 63;
  const int wv   = tid >> 6;
  const int r0   = blockIdx.x * 4;

  float xr[4][4];
  #pragma unroll
  for (int r = 0; r < 4; ++r) {
    #pragma unroll
    for (int c = 0; c < 4; ++c) {
      int i = c * 64 + lane;
      int row = r0 + r;
      xr[r][c] = (i < 128) ? ws_ui[row * 128 + i] : cand[row * 128 + (i - 128)];
    }
  }

  const int j = tid;
  const float bj = b1[j];
  float acc[4] = {bj, bj, bj, bj};

  #pragma unroll
  for (int c = 0; c < 4; ++c) {
    #pragma unroll 8
    for (int il = 0; il < 64; ++il) {
      float w = w1[(c * 64 + il) * 256 + j];
      #pragma unroll
      for (int r = 0; r < 4; ++r)
        acc[r] = fmaf(bcast_lane(xr[r][c], il), w, acc[r]);
    }
  }

  const float w2j = w2[j];
  float part[4];
  #pragma unroll
  for (int r = 0; r < 4; ++r) part[r] = fmaxf(acc[r], 0.f) * w2j;
  #pragma unroll
  for (int off = 32; off >= 1; off >>= 1) {
    #pragma unroll
    for (int r = 0; r < 4; ++r) part[r] += __shfl_xor(part[r], off, 64);
  }

  __shared__ float red[4][4];
  if (lane == 0) {
    #pragma unroll
    for (int r = 0; r < 4; ++r) red[wv][r] = part[r];
  }
  __syncthreads();
  if (tid < 4)
    out[r0 + tid] = red[0][tid] + red[1][tid] + red[2][tid] + red[3][tid] + b2[0];
}

extern "C" void kernel_launch(void* const* d_in, const int* in_sizes, int n_in,
                              void* d_out, int out_size, void* d_ws, size_t ws_size,
                              hipStream_t stream) {
  const float* behavior = (const float*)d_in[0];
  const float* cand     = (const float*)d_in[1];
  const float* fc1w     = (const float*)d_in[2];
  const float* fc1b     = (const float*)d_in[3];
  const float* fc2w     = (const float*)d_in[4];
  // d_in[5] = fc2_b: constant shift before softmax -> softmax-invariant, skipped
  const float* m1w      = (const float*)d_in[6];
  const float* m1b      = (const float*)d_in[7];
  const float* m2w      = (const float*)d_in[8];
  const float* m2b      = (const float*)d_in[9];
  float* outp  = (float*)d_out;
  float* ws_ui = (float*)d_ws;                                   // 2 MB
  short8* ws_afr = (short8*)((char*)d_ws + (size_t)BN * EN * 4); // 32 KB

  din_prep<<<32, 64, 0, stream>>>(fc1w, ws_afr);
  din_main<<<BN, 256, 0, stream>>>(behavior, cand, fc1w, fc1b, fc2w, ws_afr, ws_ui);
  din_mlp<<<BN / 4, 256, 0, stream>>>(ws_ui, cand, m1w, m1b, m2w, m2b, outp);
}